// Round 20
// baseline (607.145 us; speedup 1.0000x reference)
//
#include <hip/hip_runtime.h>
#include <hip/hip_bf16.h>

#define BB 2
#define SS 4096
#define DD 1024
#define HH 16
#define HD 64
#define FF 4096
#define MM (BB*SS)
#define QKVW 3072

typedef __hip_bfloat16 bf16;
typedef __attribute__((ext_vector_type(8))) __bf16 v8bf;
typedef __attribute__((ext_vector_type(4))) float f32x4;
typedef __attribute__((ext_vector_type(16))) float f32x16;
typedef __attribute__((ext_vector_type(8))) unsigned short u16v8;
typedef __attribute__((ext_vector_type(4))) unsigned short u16v4;

__device__ __forceinline__ f32x4 mfma16(v8bf a, v8bf b, f32x4 c) {
  return __builtin_amdgcn_mfma_f32_16x16x32_bf16(a, b, c, 0, 0, 0);
}
__device__ __forceinline__ f32x16 mfma32(v8bf a, v8bf b, f32x16 c) {
  return __builtin_amdgcn_mfma_f32_32x32x16_bf16(a, b, c, 0, 0, 0);
}
__device__ __forceinline__ void gload16(const void* g, void* l) {
  __builtin_amdgcn_global_load_lds((const __attribute__((address_space(1))) void*)g,
                                   (__attribute__((address_space(3))) void*)l, 16, 0, 0);
}
__device__ __forceinline__ unsigned cvtpk_bf16(float lo, float hi) {
  unsigned r;
  asm("v_cvt_pk_bf16_f32 %0, %1, %2" : "=v"(r) : "v"(lo), "v"(hi));
  return r;
}
__device__ __forceinline__ float fastrcp(float x) {
  float r;
  asm("v_rcp_f32 %0, %1" : "=v"(r) : "v"(x));
  return r;
}
__device__ __forceinline__ float b2f(unsigned short u) {
  union { unsigned u32; float f; } x;
  x.u32 = (unsigned)u << 16;
  return x.f;
}

// ---------------- weight transpose + fp32->bf16 ----------------
__global__ void k_tcvt(const float* __restrict__ W, bf16* __restrict__ Wt, int K, int N,
                       long rowoff, float scale)
{
  __shared__ float tile[32][33];
  const int n0 = blockIdx.x * 32, k0 = blockIdx.y * 32;
  const int tx = threadIdx.x, ty = threadIdx.y;
#pragma unroll
  for (int i = 0; i < 32; i += 8)
    tile[ty + i][tx] = W[(long)(k0 + ty + i) * N + n0 + tx];
  __syncthreads();
#pragma unroll
  for (int i = 0; i < 32; i += 8)
    Wt[(rowoff + n0 + ty + i) * K + k0 + tx] = __float2bfloat16(tile[tx][ty + i] * scale);
}

// ---------------- V transpose: qkv[M,3072] (V cols 2048+) -> Vt[B*H][64][S] ----------------
__global__ __launch_bounds__(256)
void k_vtrans(const bf16* __restrict__ qkv, bf16* __restrict__ Vt)
{
  __shared__ bf16 tile[64][72];
  const int s0 = blockIdx.x * 64;
  const int h  = blockIdx.y;
  const int b  = blockIdx.z;
  const int t  = threadIdx.x;
  const int r = t >> 3, c8 = t & 7;
#pragma unroll
  for (int it = 0; it < 2; ++it) {
    const int sr = it * 32 + r;
    const u16v8 v =
        *(const u16v8*)(qkv + (long)(b * SS + s0 + sr) * QKVW + 2048 + h * 64 + c8 * 8);
#pragma unroll
    for (int e = 0; e < 8; ++e)
      ((unsigned short*)&tile[sr][0])[c8 * 8 + e] = v[e];
  }
  __syncthreads();
#pragma unroll
  for (int it = 0; it < 2; ++it) {
    const int d = it * 32 + r;
    union { unsigned short s[8]; u16v8 v; } o;
#pragma unroll
    for (int e = 0; e < 8; ++e)
      o.s[e] = ((const unsigned short*)tile)[(c8 * 8 + e) * 72 + d];
    *(u16v8*)(Vt + ((long)(b * HH + h) * HD + d) * (long)SS + s0 + c8 * 8) = o.v;
  }
}

// ---------------- layernorm: fp32 in -> bf16 out ----------------
__global__ __launch_bounds__(256)
void k_layernorm(const float* __restrict__ x, const float* __restrict__ g,
                 const float* __restrict__ b, bf16* __restrict__ out)
{
  const int row = blockIdx.x;
  const float4 v = ((const float4*)(x + (long)row * DD))[threadIdx.x];
  float s  = v.x + v.y + v.z + v.w;
  float s2 = v.x*v.x + v.y*v.y + v.z*v.z + v.w*v.w;
#pragma unroll
  for (int off = 1; off < 64; off <<= 1) {
    s  += __shfl_xor(s,  off);
    s2 += __shfl_xor(s2, off);
  }
  __shared__ float red[8];
  if ((threadIdx.x & 63) == 0) {
    red[threadIdx.x >> 6]       = s;
    red[(threadIdx.x >> 6) + 4] = s2;
  }
  __syncthreads();
  s  = red[0] + red[1] + red[2] + red[3];
  s2 = red[4] + red[5] + red[6] + red[7];
  const float mu = s * (1.f / DD);
  const float rs = rsqrtf(s2 * (1.f / DD) - mu * mu + 1e-5f);
  const float4 gv = ((const float4*)g)[threadIdx.x];
  const float4 bv = ((const float4*)b)[threadIdx.x];
  bf16* op = out + (long)row * DD + threadIdx.x * 4;
  op[0] = __float2bfloat16((v.x - mu) * rs * gv.x + bv.x);
  op[1] = __float2bfloat16((v.y - mu) * rs * gv.y + bv.y);
  op[2] = __float2bfloat16((v.z - mu) * rs * gv.z + bv.z);
  op[3] = __float2bfloat16((v.w - mu) * rs * gv.w + bv.w);
}

// ---------------- generic bf16 GEMM ----------------
// EPI 1: fp32 out + res.  EPI 2: bf16 out, 3-segment bias select (QKV; bias0 scaled).
template<int EPI, int SWZ>
__global__ __launch_bounds__(256, 2)
void k_gemm(const bf16* __restrict__ A, const bf16* __restrict__ Bt,
            const float* __restrict__ bias, const float* __restrict__ bias2,
            const float* __restrict__ bias3, const float* __restrict__ res,
            void* __restrict__ Cout, int M, int N, int K, float scale)
{
  __shared__ __align__(16) bf16 As[128 * 32];
  __shared__ __align__(16) bf16 Bs[128 * 32];
  int bx = blockIdx.x, by = blockIdx.y;
  if (SWZ) {
    const int nwg = gridDim.x * gridDim.y;
    int o = by * gridDim.x + bx;
    o = (o & 7) * (nwg >> 3) + (o >> 3);
    bx = o % gridDim.x;
    by = o / gridDim.x;
  }
  const int t = threadIdx.x;
  const int lane = t & 63, w = t >> 6;
  const int wr = w >> 1, wc = w & 1;
  const int fr = lane & 15, fq = lane >> 4;
  const long m0 = (long)by * 128, n0 = (long)bx * 128;

  f32x4 acc[4][4] = {};

  const bf16* Ag0 = A  + (m0 + (t >> 2)) * K + (t & 3) * 8;
  const bf16* Ag1 = Ag0 + 64L * K;
  const bf16* Bg0 = Bt + (n0 + (t >> 2)) * K + (t & 3) * 8;
  const bf16* Bg1 = Bg0 + 64L * K;

  for (int kk = 0; kk < K; kk += 32) {
    gload16(Ag0 + kk, As + t * 8);
    gload16(Ag1 + kk, As + 2048 + t * 8);
    gload16(Bg0 + kk, Bs + t * 8);
    gload16(Bg1 + kk, Bs + 2048 + t * 8);
    __syncthreads();
    v8bf af[4], bfr[4];
#pragma unroll
    for (int mt = 0; mt < 4; ++mt)
      af[mt] = *(const v8bf*)&As[(wr*64 + mt*16 + fr) * 32 + fq*8];
#pragma unroll
    for (int nt = 0; nt < 4; ++nt)
      bfr[nt] = *(const v8bf*)&Bs[(wc*64 + nt*16 + fr) * 32 + fq*8];
#pragma unroll
    for (int mt = 0; mt < 4; ++mt)
#pragma unroll
      for (int nt = 0; nt < 4; ++nt)
        acc[mt][nt] = mfma16(af[mt], bfr[nt], acc[mt][nt]);
    __syncthreads();
  }

#pragma unroll
  for (int nt = 0; nt < 4; ++nt) {
    const long col = n0 + wc*64 + nt*16 + fr;
    float bv;
    if (EPI == 2) {
      const int seg = (int)(col >> 10);
      bv = (seg == 0) ? bias[col & 1023] * scale
                      : ((seg == 1) ? bias2 : bias3)[col & 1023];
    } else {
      bv = bias[col];
    }
#pragma unroll
    for (int mt = 0; mt < 4; ++mt) {
#pragma unroll
      for (int j = 0; j < 4; ++j) {
        const long row = m0 + wr*64 + mt*16 + fq*4 + j;
        const float v = acc[mt][nt][j] + bv;
        if (EPI == 2) ((bf16*)Cout)[row * N + col] = __float2bfloat16(v);
        else          ((float*)Cout)[row * N + col] = v + res[row * N + col];
      }
    }
  }
}

// ---------------- dual FFN GEMM (64-wide N): prod = sigmoid(g)*gelu(u), fast epilogue ----
__global__ __launch_bounds__(256, 2)
void k_ffn_dual(const bf16* __restrict__ A, const bf16* __restrict__ BgT,
                const bf16* __restrict__ BuT, const float* __restrict__ bgb,
                const float* __restrict__ bub, bf16* __restrict__ Out)
{
  __shared__ __align__(16) bf16 As[128 * 32];
  __shared__ __align__(16) bf16 Gs[64 * 32];
  __shared__ __align__(16) bf16 Us[64 * 32];
  const int t = threadIdx.x;
  const int lane = t & 63, w = t >> 6;
  const int wr = w >> 1, wc = w & 1;
  const int fr = lane & 15, fq = lane >> 4;
  const long m0 = (long)blockIdx.y * 128, n0 = (long)blockIdx.x * 64;
  const int K = DD;

  f32x4 ag[4][2] = {}, au[4][2] = {};

  const bf16* Ag0 = A   + (m0 + (t >> 2)) * K + (t & 3) * 8;
  const bf16* Ag1 = Ag0 + 64L * K;
  const bf16* Gg  = BgT + (n0 + (t >> 2)) * K + (t & 3) * 8;
  const bf16* Ug  = BuT + (n0 + (t >> 2)) * K + (t & 3) * 8;

  for (int kk = 0; kk < K; kk += 32) {
    gload16(Ag0 + kk, As + t * 8);
    gload16(Ag1 + kk, As + 2048 + t * 8);
    gload16(Gg + kk, Gs + t * 8);
    gload16(Ug + kk, Us + t * 8);
    __syncthreads();
    v8bf af[4], gf[2], uf[2];
#pragma unroll
    for (int mt = 0; mt < 4; ++mt)
      af[mt] = *(const v8bf*)&As[(wr*64 + mt*16 + fr) * 32 + fq*8];
#pragma unroll
    for (int nt = 0; nt < 2; ++nt) {
      gf[nt] = *(const v8bf*)&Gs[(wc*32 + nt*16 + fr) * 32 + fq*8];
      uf[nt] = *(const v8bf*)&Us[(wc*32 + nt*16 + fr) * 32 + fq*8];
    }
#pragma unroll
    for (int mt = 0; mt < 4; ++mt)
#pragma unroll
      for (int nt = 0; nt < 2; ++nt) {
        ag[mt][nt] = mfma16(af[mt], gf[nt], ag[mt][nt]);
        au[mt][nt] = mfma16(af[mt], uf[nt], au[mt][nt]);
      }
    __syncthreads();
  }

#pragma unroll
  for (int nt = 0; nt < 2; ++nt) {
    const long col = n0 + wc*32 + nt*16 + fr;
    const float gb = bgb[col], ub = bub[col];
#pragma unroll
    for (int mt = 0; mt < 4; ++mt) {
#pragma unroll
      for (int j = 0; j < 4; ++j) {
        const long row = m0 + wr*64 + mt*16 + fq*4 + j;
        const float g = ag[mt][nt][j] + gb;
        const float u = au[mt][nt][j] + ub;
        const float eg = __builtin_amdgcn_exp2f(1.44269504f * g);
        const float sg = eg * fastrcp(1.f + eg);
        const float u3 = u * u * u;
        const float E = __builtin_amdgcn_exp2f(fmaf(0.1029453f, u3, 2.3021858f * u));
        const float gl = u * E * fastrcp(1.f + E);
        Out[row * FF + col] = __float2bfloat16(sg * gl);
      }
    }
  }
}

// ---------------- flash attention, split-KV (2 splits): r15 structure ----------------
// Q/K from qkv[M,3072] (Q pre-scaled); V^T from Vt. Writes per-split normalized O (bf16)
// + per-row (m,l) in log2 domain. grid (32,16,4): z = b*2+s composed, then XCD-chunked.
__global__ __launch_bounds__(256, 2)
void k_attn(const bf16* __restrict__ qkv, const bf16* __restrict__ Vt,
            bf16* __restrict__ Osb, float* __restrict__ mlb)
{
  __shared__ __align__(16) bf16 Ksh[2][4096];
  __shared__ __align__(16) bf16 Vsh[2][4096];
  const int t = threadIdx.x;
  const int lane = t & 63, w = t >> 6;
  const int q5 = lane & 31, hi = lane >> 5;

  int o = blockIdx.x + 32 * (blockIdx.y + 16 * blockIdx.z);
  o = (o & 7) * 256 + (o >> 3);            // 2048 blocks, chunk per XCD
  const int q0 = (o & 31) * 128;
  const int h = (o >> 5) & 15;
  const int bz = o >> 9;                   // 0..3
  const int b = bz >> 1, sp = bz & 1;

  const long qkv_row0 = (long)b * SS * QKVW + h * HD;
  const long vt_base  = ((long)(b * HH + h)) * ((long)HD * SS);
  const long o_base   = ((long)sp * MM + (long)b * SS) * DD + h * HD;

  const int r0 = t >> 3;
  const int cswz = ((t & 7) * 16) ^ ((r0 & 7) << 4);
  const bf16* kg = qkv + qkv_row0 + 1024 + (long)r0 * QKVW + (cswz >> 1);
  const bf16* vg = Vt + vt_base + (long)r0 * SS + (cswz >> 1);

  v8bf qf[4];
  {
    const bf16* qp = qkv + qkv_row0 + (long)(q0 + w * 32 + q5) * QKVW + hi * 8;
#pragma unroll
    for (int c = 0; c < 4; ++c) qf[c] = *(const v8bf*)(qp + c * 16);
  }

  int kcol[4];
#pragma unroll
  for (int c = 0; c < 4; ++c)
    kcol[c] = ((c * 32 + hi * 16) ^ ((q5 & 7) << 4)) >> 1;

  float m_ = -1e30f, l_ = 0.f;
  f32x16 o0 = {}, o1 = {};

#define STAGE(bufidx, kv0_) do {                                    \
    const bf16* kp_ = kg + (long)(kv0_) * QKVW;                     \
    gload16(kp_,              &Ksh[bufidx][t * 8]);                 \
    gload16(kp_ + 32L * QKVW, &Ksh[bufidx][2048 + t * 8]);          \
    const bf16* vp_ = vg + (kv0_);                                  \
    gload16(vp_,            &Vsh[bufidx][t * 8]);                   \
    gload16(vp_ + 32L * SS, &Vsh[bufidx][2048 + t * 8]);            \
  } while (0)

  const int t0 = sp * 32, t1 = t0 + 32;
  STAGE(0, t0 * 64);
  __syncthreads();

  for (int tt = t0; tt < t1; ++tt) {
    const int cur = tt & 1;
    if (tt + 1 < t1) STAGE(cur ^ 1, (tt + 1) * 64);

    f32x16 s0 = {}, s1 = {};
#pragma unroll
    for (int c = 0; c < 4; ++c) {
      const v8bf k0 = *(const v8bf*)&Ksh[cur][q5 * 64 + kcol[c]];
      const v8bf k1 = *(const v8bf*)&Ksh[cur][(32 + q5) * 64 + kcol[c]];
      s0 = mfma32(k0, qf[c], s0);
      s1 = mfma32(k1, qf[c], s1);
    }

    // tree max (depth ~5)
    float tm[8];
#pragma unroll
    for (int r = 0; r < 8; ++r)
      tm[r] = fmaxf(fmaxf(s0[r], s0[r + 8]), fmaxf(s1[r], s1[r + 8]));
#pragma unroll
    for (int r = 0; r < 4; ++r) tm[r] = fmaxf(tm[r], tm[r + 4]);
    float pm = fmaxf(fmaxf(tm[0], tm[1]), fmaxf(tm[2], tm[3]));
    pm = fmaxf(pm, __shfl_xor(pm, 32));

    const bool defer = __all(pm - m_ <= 8.f);
    float al = 1.f;
    if (!defer) {
      const float mn = fmaxf(m_, pm);
      al = __builtin_amdgcn_exp2f(m_ - mn);
      m_ = mn;
    }
#pragma unroll
    for (int r = 0; r < 16; ++r) s0[r] = __builtin_amdgcn_exp2f(s0[r] - m_);
#pragma unroll
    for (int r = 0; r < 16; ++r) s1[r] = __builtin_amdgcn_exp2f(s1[r] - m_);
    // 4-accumulator sum
    float a0, a1, a2, a3;
    a0 = s0[0] + s1[0]; a1 = s0[1] + s1[1]; a2 = s0[2] + s1[2]; a3 = s0[3] + s1[3];
#pragma unroll
    for (int r = 4; r < 16; r += 4) {
      a0 += s0[r] + s1[r];
      a1 += s0[r + 1] + s1[r + 1];
      a2 += s0[r + 2] + s1[r + 2];
      a3 += s0[r + 3] + s1[r + 3];
    }
    float rs = (a0 + a1) + (a2 + a3);
    rs += __shfl_xor(rs, 32);
    if (defer) {
      l_ += rs;
    } else {
      l_ = l_ * al + rs;
#pragma unroll
      for (int r = 0; r < 16; ++r) { o0[r] *= al; o1[r] *= al; }
    }

    v8bf pb[4];
#pragma unroll
    for (int c = 0; c < 4; ++c) {
      const int base = (c & 1) * 8;
      unsigned wa0, wa1, wb0, wb1;
      if (c < 2) {
        wa0 = cvtpk_bf16(s0[base + 0], s0[base + 1]);
        wa1 = cvtpk_bf16(s0[base + 2], s0[base + 3]);
        wb0 = cvtpk_bf16(s0[base + 4], s0[base + 5]);
        wb1 = cvtpk_bf16(s0[base + 6], s0[base + 7]);
      } else {
        wa0 = cvtpk_bf16(s1[base + 0], s1[base + 1]);
        wa1 = cvtpk_bf16(s1[base + 2], s1[base + 3]);
        wb0 = cvtpk_bf16(s1[base + 4], s1[base + 5]);
        wb1 = cvtpk_bf16(s1[base + 6], s1[base + 7]);
      }
      asm("v_permlane32_swap_b32 %0, %1" : "+v"(wa0), "+v"(wb0));
      asm("v_permlane32_swap_b32 %0, %1" : "+v"(wa1), "+v"(wb1));
      union { unsigned u[4]; v8bf v; } cvt;
      cvt.u[0] = wa0; cvt.u[1] = wa1; cvt.u[2] = wb0; cvt.u[3] = wb1;
      pb[c] = cvt.v;
    }

#pragma unroll
    for (int c = 0; c < 4; ++c) {
      const v8bf v0f = *(const v8bf*)&Vsh[cur][q5 * 64 + kcol[c]];
      const v8bf v1f = *(const v8bf*)&Vsh[cur][(32 + q5) * 64 + kcol[c]];
      o0 = mfma32(v0f, pb[c], o0);
      o1 = mfma32(v1f, pb[c], o1);
    }
    __syncthreads();
  }
#undef STAGE

  // per-row (m, l) for the combine (log2 domain)
  if (hi == 0) {
    const int row = q0 + w * 32 + q5;
    const long mi = ((((long)sp * BB + b) * HH + h) * SS + row) * 2;
    mlb[mi] = m_;
    mlb[mi + 1] = l_;
  }

  const float inv = 1.f / l_;
  bf16* Osh = &Ksh[0][0];
  const int qrow = w * 32 + q5;
  const int oswz = (qrow & 7) << 4;
#pragma unroll
  for (int r = 0; r < 16; ++r) {
    const int d0 = (r & 3) + 8 * (r >> 2) + 4 * hi;
    Osh[((qrow * 128 + d0 * 2) ^ oswz) >> 1]        = __float2bfloat16(o0[r] * inv);
    Osh[((qrow * 128 + (32 + d0) * 2) ^ oswz) >> 1] = __float2bfloat16(o1[r] * inv);
  }
  __syncthreads();
  {
    const int q = t >> 1, half = t & 1;
    const int qs = (q & 7) << 4;
    bf16* cp = Osb + o_base + (long)(q0 + q) * DD + half * 32;
#pragma unroll
    for (int s = 0; s < 4; ++s) {
      const int byte = (q * 128 + half * 64 + s * 16) ^ qs;
      *(u16v8*)(cp + s * 8) = *(const u16v8*)&Osh[byte >> 1];
    }
  }
}

// ---------------- combine: ctx = (W1*O1 + W2*O2) / (W1+W2), Wi = 2^(mi-m)*li -----------
__global__ __launch_bounds__(256)
void k_comb(const bf16* __restrict__ Osb, const float* __restrict__ mlb,
            bf16* __restrict__ ctx)
{
  const int row = blockIdx.x;              // 0..MM-1
  const int b = row >> 12, sr = row & (SS - 1);
  const int t = threadIdx.x;
  const int e0 = t * 4;
  const int h = e0 >> 6;
  const long i1 = (((long)(0 * BB + b) * HH + h) * SS + sr) * 2;
  const long i2 = (((long)(1 * BB + b) * HH + h) * SS + sr) * 2;
  const float m1 = mlb[i1], l1 = mlb[i1 + 1];
  const float m2 = mlb[i2], l2 = mlb[i2 + 1];
  const float m = fmaxf(m1, m2);
  const float W1 = __builtin_amdgcn_exp2f(m1 - m) * l1;
  const float W2 = __builtin_amdgcn_exp2f(m2 - m) * l2;
  const float inv = fastrcp(W1 + W2);
  const float c1 = W1 * inv, c2 = W2 * inv;
  const long off = (long)row * DD + e0;
  const u16v4 a = *(const u16v4*)(Osb + off);
  const u16v4 c = *(const u16v4*)(Osb + (long)MM * DD + off);
  u16v4 outv;
#pragma unroll
  for (int i = 0; i < 4; ++i) {
    const float v = c1 * b2f(a[i]) + c2 * b2f(c[i]);
    union { bf16 bh; unsigned short us; } cv;
    cv.bh = __float2bfloat16(v);
    outv[i] = cv.us;
  }
  *(u16v4*)(ctx + off) = outv;
}

// ---------------- host ----------------
extern "C" void kernel_launch(void* const* d_in, const int* in_sizes, int n_in,
                              void* d_out, int out_size, void* d_ws, size_t ws_size,
                              hipStream_t stream)
{
  const float* x    = (const float*)d_in[0];
  const float* wq   = (const float*)d_in[1];
  const float* bq   = (const float*)d_in[2];
  const float* wk   = (const float*)d_in[3];
  const float* bk   = (const float*)d_in[4];
  const float* wv   = (const float*)d_in[5];
  const float* bv   = (const float*)d_in[6];
  const float* wo   = (const float*)d_in[7];
  const float* bo   = (const float*)d_in[8];
  const float* ln1g = (const float*)d_in[9];
  const float* ln1b = (const float*)d_in[10];
  const float* lnfg = (const float*)d_in[11];
  const float* lnfb = (const float*)d_in[12];
  const float* w1   = (const float*)d_in[13];
  const float* b1   = (const float*)d_in[14];
  const float* wg   = (const float*)d_in[15];
  const float* bg   = (const float*)d_in[16];
  const float* w2   = (const float*)d_in[17];
  const float* b2   = (const float*)d_in[18];

  char* ws = (char*)d_ws;
  const size_t MB = 1u << 20;
  bf16*  WqkvT = (bf16*)(ws + 0 * MB);    // [3072][1024] 6MB (wq pre-scaled by qscale)
  bf16*  WoT   = (bf16*)(ws + 6 * MB);
  bf16*  W1T   = (bf16*)(ws + 8 * MB);
  bf16*  WgT   = (bf16*)(ws + 16 * MB);
  bf16*  W2T   = (bf16*)(ws + 24 * MB);
  float* x1    = (float*)(ws + 32 * MB);  // 32MB; doubles as O-split buffer during attn
  bf16*  Osb   = (bf16*)(ws + 32 * MB);   // [2][M][1024] bf16 = 32MB (dead before x1 use)
  bf16*  hbuf  = (bf16*)(ws + 64 * MB);   // h / ctx / h2 (disjoint lifetimes)
  bf16*  QKVb  = (bf16*)(ws + 80 * MB);   // [8192][3072] 48MB
  bf16*  Vtb   = (bf16*)(ws + 128 * MB);  // [B*H][64][S] 16MB
  bf16*  ctxb  = hbuf;
  bf16*  prod  = (bf16*)(ws + 80 * MB);   // 64MB, overlaps QKVb+Vtb (dead by then)
  float* mlb   = (float*)d_out;           // 4MB of d_out; overwritten by final GEMM

  const float qscale = 0.1803368801111204f;  // log2(e) / sqrt(64)

  dim3 tb(32, 8);
  k_tcvt<<<dim3(32, 32), tb, 0, stream>>>(wq, WqkvT, 1024, 1024, 0, qscale);
  k_tcvt<<<dim3(32, 32), tb, 0, stream>>>(wk, WqkvT, 1024, 1024, 1024, 1.f);
  k_tcvt<<<dim3(32, 32), tb, 0, stream>>>(wv, WqkvT, 1024, 1024, 2048, 1.f);
  k_tcvt<<<dim3(32, 32), tb, 0, stream>>>(wo, WoT, 1024, 1024, 0, 1.f);
  k_tcvt<<<dim3(128, 32), tb, 0, stream>>>(w1, W1T, 1024, 4096, 0, 1.f);
  k_tcvt<<<dim3(128, 32), tb, 0, stream>>>(wg, WgT, 1024, 4096, 0, 1.f);
  k_tcvt<<<dim3(32, 128), tb, 0, stream>>>(w2, W2T, 4096, 1024, 0, 1.f);

  k_layernorm<<<MM, 256, 0, stream>>>(x, ln1g, ln1b, hbuf);

  k_gemm<2,0><<<dim3(QKVW / 128, MM / 128), 256, 0, stream>>>(
      hbuf, WqkvT, bq, bk, bv, nullptr, QKVb, MM, QKVW, 1024, qscale);

  k_vtrans<<<dim3(SS / 64, HH, BB), 256, 0, stream>>>(QKVb, Vtb);
  k_attn<<<dim3(SS / 128, HH, 2 * BB), 256, 0, stream>>>(QKVb, Vtb, Osb, mlb);
  k_comb<<<MM, 256, 0, stream>>>(Osb, mlb, ctxb);

  k_gemm<1,0><<<dim3(8, 64), 256, 0, stream>>>(
      ctxb, WoT, bo, nullptr, nullptr, x, x1, MM, 1024, 1024, 1.f);

  k_layernorm<<<MM, 256, 0, stream>>>(x1, lnfg, lnfb, hbuf);

  k_ffn_dual<<<dim3(FF / 64, MM / 128), 256, 0, stream>>>(hbuf, WgT, W1T, bg, b1, prod);

  k_gemm<1,0><<<dim3(8, 64), 256, 0, stream>>>(
      prod, W2T, b2, nullptr, nullptr, x1, (float*)d_out, MM, 1024, 4096, 1.f);
}

// Round 21
// 558.983 us; speedup vs baseline: 1.0862x; 1.0862x over previous
//
#include <hip/hip_runtime.h>
#include <hip/hip_bf16.h>

#define BB 2
#define SS 4096
#define DD 1024
#define HH 16
#define HD 64
#define FF 4096
#define MM (BB*SS)
#define QKVW 3072

typedef __hip_bfloat16 bf16;
typedef __attribute__((ext_vector_type(8))) __bf16 v8bf;
typedef __attribute__((ext_vector_type(4))) float f32x4;
typedef __attribute__((ext_vector_type(16))) float f32x16;
typedef __attribute__((ext_vector_type(8))) unsigned short u16v8;

__device__ __forceinline__ f32x4 mfma16(v8bf a, v8bf b, f32x4 c) {
  return __builtin_amdgcn_mfma_f32_16x16x32_bf16(a, b, c, 0, 0, 0);
}
__device__ __forceinline__ f32x16 mfma32(v8bf a, v8bf b, f32x16 c) {
  return __builtin_amdgcn_mfma_f32_32x32x16_bf16(a, b, c, 0, 0, 0);
}
__device__ __forceinline__ void gload16(const void* g, void* l) {
  __builtin_amdgcn_global_load_lds((const __attribute__((address_space(1))) void*)g,
                                   (__attribute__((address_space(3))) void*)l, 16, 0, 0);
}
__device__ __forceinline__ unsigned cvtpk_bf16(float lo, float hi) {
  unsigned r;
  asm("v_cvt_pk_bf16_f32 %0, %1, %2" : "=v"(r) : "v"(lo), "v"(hi));
  return r;
}
__device__ __forceinline__ float fastrcp(float x) {
  float r;
  asm("v_rcp_f32 %0, %1" : "=v"(r) : "v"(x));
  return r;
}

// ---------------- weight transpose + fp32->bf16 ----------------
__global__ void k_tcvt(const float* __restrict__ W, bf16* __restrict__ Wt, int K, int N,
                       long rowoff, float scale)
{
  __shared__ float tile[32][33];
  const int n0 = blockIdx.x * 32, k0 = blockIdx.y * 32;
  const int tx = threadIdx.x, ty = threadIdx.y;
#pragma unroll
  for (int i = 0; i < 32; i += 8)
    tile[ty + i][tx] = W[(long)(k0 + ty + i) * N + n0 + tx];
  __syncthreads();
#pragma unroll
  for (int i = 0; i < 32; i += 8)
    Wt[(rowoff + n0 + ty + i) * K + k0 + tx] = __float2bfloat16(tile[tx][ty + i] * scale);
}

// ---------------- V transpose: qkv[M,3072] (V cols 2048+) -> Vt[B*H][64][S] ----------------
__global__ __launch_bounds__(256)
void k_vtrans(const bf16* __restrict__ qkv, bf16* __restrict__ Vt)
{
  __shared__ bf16 tile[64][72];
  const int s0 = blockIdx.x * 64;
  const int h  = blockIdx.y;
  const int b  = blockIdx.z;
  const int t  = threadIdx.x;
  const int r = t >> 3, c8 = t & 7;
#pragma unroll
  for (int it = 0; it < 2; ++it) {
    const int sr = it * 32 + r;
    const u16v8 v =
        *(const u16v8*)(qkv + (long)(b * SS + s0 + sr) * QKVW + 2048 + h * 64 + c8 * 8);
#pragma unroll
    for (int e = 0; e < 8; ++e)
      ((unsigned short*)&tile[sr][0])[c8 * 8 + e] = v[e];
  }
  __syncthreads();
#pragma unroll
  for (int it = 0; it < 2; ++it) {
    const int d = it * 32 + r;
    union { unsigned short s[8]; u16v8 v; } o;
#pragma unroll
    for (int e = 0; e < 8; ++e)
      o.s[e] = ((const unsigned short*)tile)[(c8 * 8 + e) * 72 + d];
    *(u16v8*)(Vt + ((long)(b * HH + h) * HD + d) * (long)SS + s0 + c8 * 8) = o.v;
  }
}

// ---------------- layernorm: fp32 in -> bf16 out ----------------
__global__ __launch_bounds__(256)
void k_layernorm(const float* __restrict__ x, const float* __restrict__ g,
                 const float* __restrict__ b, bf16* __restrict__ out)
{
  const int row = blockIdx.x;
  const float4 v = ((const float4*)(x + (long)row * DD))[threadIdx.x];
  float s  = v.x + v.y + v.z + v.w;
  float s2 = v.x*v.x + v.y*v.y + v.z*v.z + v.w*v.w;
#pragma unroll
  for (int off = 1; off < 64; off <<= 1) {
    s  += __shfl_xor(s,  off);
    s2 += __shfl_xor(s2, off);
  }
  __shared__ float red[8];
  if ((threadIdx.x & 63) == 0) {
    red[threadIdx.x >> 6]       = s;
    red[(threadIdx.x >> 6) + 4] = s2;
  }
  __syncthreads();
  s  = red[0] + red[1] + red[2] + red[3];
  s2 = red[4] + red[5] + red[6] + red[7];
  const float mu = s * (1.f / DD);
  const float rs = rsqrtf(s2 * (1.f / DD) - mu * mu + 1e-5f);
  const float4 gv = ((const float4*)g)[threadIdx.x];
  const float4 bv = ((const float4*)b)[threadIdx.x];
  bf16* op = out + (long)row * DD + threadIdx.x * 4;
  op[0] = __float2bfloat16((v.x - mu) * rs * gv.x + bv.x);
  op[1] = __float2bfloat16((v.y - mu) * rs * gv.y + bv.y);
  op[2] = __float2bfloat16((v.z - mu) * rs * gv.z + bv.z);
  op[3] = __float2bfloat16((v.w - mu) * rs * gv.w + bv.w);
}

// ---------------- generic bf16 GEMM, BK=64 + XOR swizzle ----------------
// EPI 1: fp32 out + res.  EPI 2: bf16 out, 3-segment bias select (QKV; bias0 scaled).
template<int EPI, int SWZ>
__global__ __launch_bounds__(256, 2)
void k_gemm(const bf16* __restrict__ A, const bf16* __restrict__ Bt,
            const float* __restrict__ bias, const float* __restrict__ bias2,
            const float* __restrict__ bias3, const float* __restrict__ res,
            void* __restrict__ Cout, int M, int N, int K, float scale)
{
  __shared__ __align__(16) bf16 As[128 * 64];
  __shared__ __align__(16) bf16 Bs[128 * 64];
  int bx = blockIdx.x, by = blockIdx.y;
  if (SWZ) {
    const int nwg = gridDim.x * gridDim.y;
    int o = by * gridDim.x + bx;
    o = (o & 7) * (nwg >> 3) + (o >> 3);
    bx = o % gridDim.x;
    by = o / gridDim.x;
  }
  const int t = threadIdx.x;
  const int lane = t & 63, w = t >> 6;
  const int wr = w >> 1, wc = w & 1;
  const int fr = lane & 15, fq = lane >> 4;
  const long m0 = (long)by * 128, n0 = (long)bx * 128;

  f32x4 acc[4][4] = {};

  // staging: 32 rows/pass x 64 cols; source col pre-swizzled within 128B row group
  const int r0 = t >> 3;
  const int cswz = ((t & 7) * 16) ^ ((r0 & 7) << 4);   // bytes
  const bf16* Ag = A  + (m0 + r0) * K + (cswz >> 1);
  const bf16* Bg = Bt + (n0 + r0) * K + (cswz >> 1);

  for (int kk = 0; kk < K; kk += 64) {
#pragma unroll
    for (int ch = 0; ch < 4; ++ch) {
      gload16(Ag + (long)ch * 32 * K + kk, As + ch * 2048 + t * 8);
      gload16(Bg + (long)ch * 32 * K + kk, Bs + ch * 2048 + t * 8);
    }
    __syncthreads();
#pragma unroll
    for (int ks = 0; ks < 2; ++ks) {
      v8bf af[4], bfr[4];
#pragma unroll
      for (int mt = 0; mt < 4; ++mt) {
        const int rr = wr*64 + mt*16 + fr;
        af[mt] = *(const v8bf*)&As[rr*64 + (((ks*64 + fq*16) ^ ((rr & 7) << 4)) >> 1)];
      }
#pragma unroll
      for (int nt = 0; nt < 4; ++nt) {
        const int rr = wc*64 + nt*16 + fr;
        bfr[nt] = *(const v8bf*)&Bs[rr*64 + (((ks*64 + fq*16) ^ ((rr & 7) << 4)) >> 1)];
      }
#pragma unroll
      for (int mt = 0; mt < 4; ++mt)
#pragma unroll
        for (int nt = 0; nt < 4; ++nt)
          acc[mt][nt] = mfma16(af[mt], bfr[nt], acc[mt][nt]);
    }
    __syncthreads();
  }

#pragma unroll
  for (int nt = 0; nt < 4; ++nt) {
    const long col = n0 + wc*64 + nt*16 + fr;
    float bv;
    if (EPI == 2) {
      const int seg = (int)(col >> 10);
      bv = (seg == 0) ? bias[col & 1023] * scale
                      : ((seg == 1) ? bias2 : bias3)[col & 1023];
    } else {
      bv = bias[col];
    }
#pragma unroll
    for (int mt = 0; mt < 4; ++mt) {
#pragma unroll
      for (int j = 0; j < 4; ++j) {
        const long row = m0 + wr*64 + mt*16 + fq*4 + j;
        const float v = acc[mt][nt][j] + bv;
        if (EPI == 2) ((bf16*)Cout)[row * N + col] = __float2bfloat16(v);
        else          ((float*)Cout)[row * N + col] = v + res[row * N + col];
      }
    }
  }
}

// ---------------- dual FFN GEMM (64-wide N), BK=64 + XOR swizzle ----------------
__global__ __launch_bounds__(256, 2)
void k_ffn_dual(const bf16* __restrict__ A, const bf16* __restrict__ BgT,
                const bf16* __restrict__ BuT, const float* __restrict__ bgb,
                const float* __restrict__ bub, bf16* __restrict__ Out)
{
  __shared__ __align__(16) bf16 As[128 * 64];
  __shared__ __align__(16) bf16 Gs[64 * 64];
  __shared__ __align__(16) bf16 Us[64 * 64];
  const int t = threadIdx.x;
  const int lane = t & 63, w = t >> 6;
  const int wr = w >> 1, wc = w & 1;
  const int fr = lane & 15, fq = lane >> 4;
  const long m0 = (long)blockIdx.y * 128, n0 = (long)blockIdx.x * 64;
  const int K = DD;

  f32x4 ag[4][2] = {}, au[4][2] = {};

  const int r0 = t >> 3;
  const int cswz = ((t & 7) * 16) ^ ((r0 & 7) << 4);
  const bf16* Ag = A   + (m0 + r0) * K + (cswz >> 1);
  const bf16* Gg = BgT + (n0 + r0) * K + (cswz >> 1);
  const bf16* Ug = BuT + (n0 + r0) * K + (cswz >> 1);

  for (int kk = 0; kk < K; kk += 64) {
#pragma unroll
    for (int ch = 0; ch < 4; ++ch)
      gload16(Ag + (long)ch * 32 * K + kk, As + ch * 2048 + t * 8);
#pragma unroll
    for (int ch = 0; ch < 2; ++ch) {
      gload16(Gg + (long)ch * 32 * K + kk, Gs + ch * 2048 + t * 8);
      gload16(Ug + (long)ch * 32 * K + kk, Us + ch * 2048 + t * 8);
    }
    __syncthreads();
#pragma unroll
    for (int ks = 0; ks < 2; ++ks) {
      v8bf af[4], gf[2], uf[2];
#pragma unroll
      for (int mt = 0; mt < 4; ++mt) {
        const int rr = wr*64 + mt*16 + fr;
        af[mt] = *(const v8bf*)&As[rr*64 + (((ks*64 + fq*16) ^ ((rr & 7) << 4)) >> 1)];
      }
#pragma unroll
      for (int nt = 0; nt < 2; ++nt) {
        const int rr = wc*32 + nt*16 + fr;
        const int ce = (((ks*64 + fq*16) ^ ((rr & 7) << 4)) >> 1);
        gf[nt] = *(const v8bf*)&Gs[rr*64 + ce];
        uf[nt] = *(const v8bf*)&Us[rr*64 + ce];
      }
#pragma unroll
      for (int mt = 0; mt < 4; ++mt)
#pragma unroll
        for (int nt = 0; nt < 2; ++nt) {
          ag[mt][nt] = mfma16(af[mt], gf[nt], ag[mt][nt]);
          au[mt][nt] = mfma16(af[mt], uf[nt], au[mt][nt]);
        }
    }
    __syncthreads();
  }

#pragma unroll
  for (int nt = 0; nt < 2; ++nt) {
    const long col = n0 + wc*32 + nt*16 + fr;
    const float gb = bgb[col], ub = bub[col];
#pragma unroll
    for (int mt = 0; mt < 4; ++mt) {
#pragma unroll
      for (int j = 0; j < 4; ++j) {
        const long row = m0 + wr*64 + mt*16 + fq*4 + j;
        const float g = ag[mt][nt][j] + gb;
        const float u = au[mt][nt][j] + ub;
        const float eg = __builtin_amdgcn_exp2f(1.44269504f * g);
        const float sg = eg * fastrcp(1.f + eg);
        const float u3 = u * u * u;
        const float E = __builtin_amdgcn_exp2f(fmaf(0.1029453f, u3, 2.3021858f * u));
        const float gl = u * E * fastrcp(1.f + E);
        Out[row * FF + col] = __float2bfloat16(sg * gl);
      }
    }
  }
}

// ---------------- flash attention (r15 structure) ----------------
// Q/K from qkv[M,3072] (Q pre-scaled); V^T from Vt. Tree max + defer-max softmax.
__global__ __launch_bounds__(256, 2)
void k_attn(const bf16* __restrict__ qkv, const bf16* __restrict__ Vt,
            bf16* __restrict__ ctx)
{
  __shared__ __align__(16) bf16 Ksh[2][4096];
  __shared__ __align__(16) bf16 Vsh[2][4096];
  const int t = threadIdx.x;
  const int lane = t & 63, w = t >> 6;
  const int q5 = lane & 31, hi = lane >> 5;

  int o = blockIdx.x + 32 * (blockIdx.y + 16 * blockIdx.z);
  o = (o & 7) * 128 + (o >> 3);            // 1024 blocks, chunk per XCD
  const int q0 = (o & 31) * 128;
  const int h = (o >> 5) & 15, b = o >> 9;

  const long qkv_row0 = (long)b * SS * QKVW + h * HD;
  const long ctx_base = (long)b * SS * DD + h * HD;
  const long vt_base  = ((long)(b * HH + h)) * ((long)HD * SS);

  const int r0 = t >> 3;
  const int cswz = ((t & 7) * 16) ^ ((r0 & 7) << 4);
  const bf16* kg = qkv + qkv_row0 + 1024 + (long)r0 * QKVW + (cswz >> 1);
  const bf16* vg = Vt + vt_base + (long)r0 * SS + (cswz >> 1);

  v8bf qf[4];
  {
    const bf16* qp = qkv + qkv_row0 + (long)(q0 + w * 32 + q5) * QKVW + hi * 8;
#pragma unroll
    for (int c = 0; c < 4; ++c) qf[c] = *(const v8bf*)(qp + c * 16);
  }

  int kcol[4];
#pragma unroll
  for (int c = 0; c < 4; ++c)
    kcol[c] = ((c * 32 + hi * 16) ^ ((q5 & 7) << 4)) >> 1;

  float m_ = -1e30f, l_ = 0.f;
  f32x16 o0 = {}, o1 = {};

#define STAGE(bufidx, kv0_) do {                                    \
    const bf16* kp_ = kg + (long)(kv0_) * QKVW;                     \
    gload16(kp_,              &Ksh[bufidx][t * 8]);                 \
    gload16(kp_ + 32L * QKVW, &Ksh[bufidx][2048 + t * 8]);          \
    const bf16* vp_ = vg + (kv0_);                                  \
    gload16(vp_,            &Vsh[bufidx][t * 8]);                   \
    gload16(vp_ + 32L * SS, &Vsh[bufidx][2048 + t * 8]);            \
  } while (0)

  STAGE(0, 0);
  __syncthreads();

  for (int tt = 0; tt < SS / 64; ++tt) {
    const int cur = tt & 1;
    if (tt + 1 < SS / 64) STAGE(cur ^ 1, (tt + 1) * 64);

    f32x16 s0 = {}, s1 = {};
#pragma unroll
    for (int c = 0; c < 4; ++c) {
      const v8bf k0 = *(const v8bf*)&Ksh[cur][q5 * 64 + kcol[c]];
      const v8bf k1 = *(const v8bf*)&Ksh[cur][(32 + q5) * 64 + kcol[c]];
      s0 = mfma32(k0, qf[c], s0);
      s1 = mfma32(k1, qf[c], s1);
    }

    // tree max (depth ~5)
    float tm[8];
#pragma unroll
    for (int r = 0; r < 8; ++r)
      tm[r] = fmaxf(fmaxf(s0[r], s0[r + 8]), fmaxf(s1[r], s1[r + 8]));
#pragma unroll
    for (int r = 0; r < 4; ++r) tm[r] = fmaxf(tm[r], tm[r + 4]);
    float pm = fmaxf(fmaxf(tm[0], tm[1]), fmaxf(tm[2], tm[3]));
    pm = fmaxf(pm, __shfl_xor(pm, 32));

    const bool defer = __all(pm - m_ <= 8.f);
    float al = 1.f;
    if (!defer) {
      const float mn = fmaxf(m_, pm);
      al = __builtin_amdgcn_exp2f(m_ - mn);
      m_ = mn;
    }
#pragma unroll
    for (int r = 0; r < 16; ++r) s0[r] = __builtin_amdgcn_exp2f(s0[r] - m_);
#pragma unroll
    for (int r = 0; r < 16; ++r) s1[r] = __builtin_amdgcn_exp2f(s1[r] - m_);
    // 4-accumulator sum (4 chains of 8 + tree tail)
    float a0, a1, a2, a3;
    a0 = s0[0] + s1[0]; a1 = s0[1] + s1[1]; a2 = s0[2] + s1[2]; a3 = s0[3] + s1[3];
#pragma unroll
    for (int r = 4; r < 16; r += 4) {
      a0 += s0[r] + s1[r];
      a1 += s0[r + 1] + s1[r + 1];
      a2 += s0[r + 2] + s1[r + 2];
      a3 += s0[r + 3] + s1[r + 3];
    }
    float rs = (a0 + a1) + (a2 + a3);
    rs += __shfl_xor(rs, 32);
    if (defer) {
      l_ += rs;
    } else {
      l_ = l_ * al + rs;
#pragma unroll
      for (int r = 0; r < 16; ++r) { o0[r] *= al; o1[r] *= al; }
    }

    v8bf pb[4];
#pragma unroll
    for (int c = 0; c < 4; ++c) {
      const int base = (c & 1) * 8;
      unsigned wa0, wa1, wb0, wb1;
      if (c < 2) {
        wa0 = cvtpk_bf16(s0[base + 0], s0[base + 1]);
        wa1 = cvtpk_bf16(s0[base + 2], s0[base + 3]);
        wb0 = cvtpk_bf16(s0[base + 4], s0[base + 5]);
        wb1 = cvtpk_bf16(s0[base + 6], s0[base + 7]);
      } else {
        wa0 = cvtpk_bf16(s1[base + 0], s1[base + 1]);
        wa1 = cvtpk_bf16(s1[base + 2], s1[base + 3]);
        wb0 = cvtpk_bf16(s1[base + 4], s1[base + 5]);
        wb1 = cvtpk_bf16(s1[base + 6], s1[base + 7]);
      }
      asm("v_permlane32_swap_b32 %0, %1" : "+v"(wa0), "+v"(wb0));
      asm("v_permlane32_swap_b32 %0, %1" : "+v"(wa1), "+v"(wb1));
      union { unsigned u[4]; v8bf v; } cvt;
      cvt.u[0] = wa0; cvt.u[1] = wa1; cvt.u[2] = wb0; cvt.u[3] = wb1;
      pb[c] = cvt.v;
    }

#pragma unroll
    for (int c = 0; c < 4; ++c) {
      const v8bf v0f = *(const v8bf*)&Vsh[cur][q5 * 64 + kcol[c]];
      const v8bf v1f = *(const v8bf*)&Vsh[cur][(32 + q5) * 64 + kcol[c]];
      o0 = mfma32(v0f, pb[c], o0);
      o1 = mfma32(v1f, pb[c], o1);
    }
    __syncthreads();
  }
#undef STAGE

  const float inv = 1.f / l_;
  bf16* Osh = &Ksh[0][0];
  const int qrow = w * 32 + q5;
  const int oswz = (qrow & 7) << 4;
#pragma unroll
  for (int r = 0; r < 16; ++r) {
    const int d0 = (r & 3) + 8 * (r >> 2) + 4 * hi;
    Osh[((qrow * 128 + d0 * 2) ^ oswz) >> 1]        = __float2bfloat16(o0[r] * inv);
    Osh[((qrow * 128 + (32 + d0) * 2) ^ oswz) >> 1] = __float2bfloat16(o1[r] * inv);
  }
  __syncthreads();
  {
    const int q = t >> 1, half = t & 1;
    const int qs = (q & 7) << 4;
    bf16* cp = ctx + ctx_base + (long)(q0 + q) * DD + half * 32;
#pragma unroll
    for (int s = 0; s < 4; ++s) {
      const int byte = (q * 128 + half * 64 + s * 16) ^ qs;
      *(u16v8*)(cp + s * 8) = *(const u16v8*)&Osh[byte >> 1];
    }
  }
}

// ---------------- host ----------------
extern "C" void kernel_launch(void* const* d_in, const int* in_sizes, int n_in,
                              void* d_out, int out_size, void* d_ws, size_t ws_size,
                              hipStream_t stream)
{
  const float* x    = (const float*)d_in[0];
  const float* wq   = (const float*)d_in[1];
  const float* bq   = (const float*)d_in[2];
  const float* wk   = (const float*)d_in[3];
  const float* bk   = (const float*)d_in[4];
  const float* wv   = (const float*)d_in[5];
  const float* bv   = (const float*)d_in[6];
  const float* wo   = (const float*)d_in[7];
  const float* bo   = (const float*)d_in[8];
  const float* ln1g = (const float*)d_in[9];
  const float* ln1b = (const float*)d_in[10];
  const float* lnfg = (const float*)d_in[11];
  const float* lnfb = (const float*)d_in[12];
  const float* w1   = (const float*)d_in[13];
  const float* b1   = (const float*)d_in[14];
  const float* wg   = (const float*)d_in[15];
  const float* bg   = (const float*)d_in[16];
  const float* w2   = (const float*)d_in[17];
  const float* b2   = (const float*)d_in[18];

  char* ws = (char*)d_ws;
  const size_t MB = 1u << 20;
  bf16*  WqkvT = (bf16*)(ws + 0 * MB);    // [3072][1024] 6MB (wq pre-scaled by qscale)
  bf16*  WoT   = (bf16*)(ws + 6 * MB);
  bf16*  W1T   = (bf16*)(ws + 8 * MB);
  bf16*  WgT   = (bf16*)(ws + 16 * MB);
  bf16*  W2T   = (bf16*)(ws + 24 * MB);
  float* x1    = (float*)(ws + 32 * MB);
  bf16*  hbuf  = (bf16*)(ws + 64 * MB);   // h / ctx / h2 (disjoint lifetimes)
  bf16*  QKVb  = (bf16*)(ws + 80 * MB);   // [8192][3072] 48MB
  bf16*  Vtb   = (bf16*)(ws + 128 * MB);  // [B*H][64][S] 16MB
  bf16*  ctxb  = hbuf;
  bf16*  prod  = (bf16*)(ws + 80 * MB);   // 64MB, overlaps QKVb+Vtb (dead by then)

  const float qscale = 0.1803368801111204f;  // log2(e) / sqrt(64)

  dim3 tb(32, 8);
  k_tcvt<<<dim3(32, 32), tb, 0, stream>>>(wq, WqkvT, 1024, 1024, 0, qscale);
  k_tcvt<<<dim3(32, 32), tb, 0, stream>>>(wk, WqkvT, 1024, 1024, 1024, 1.f);
  k_tcvt<<<dim3(32, 32), tb, 0, stream>>>(wv, WqkvT, 1024, 1024, 2048, 1.f);
  k_tcvt<<<dim3(32, 32), tb, 0, stream>>>(wo, WoT, 1024, 1024, 0, 1.f);
  k_tcvt<<<dim3(128, 32), tb, 0, stream>>>(w1, W1T, 1024, 4096, 0, 1.f);
  k_tcvt<<<dim3(128, 32), tb, 0, stream>>>(wg, WgT, 1024, 4096, 0, 1.f);
  k_tcvt<<<dim3(32, 128), tb, 0, stream>>>(w2, W2T, 4096, 1024, 0, 1.f);

  k_layernorm<<<MM, 256, 0, stream>>>(x, ln1g, ln1b, hbuf);

  k_gemm<2,0><<<dim3(QKVW / 128, MM / 128), 256, 0, stream>>>(
      hbuf, WqkvT, bq, bk, bv, nullptr, QKVb, MM, QKVW, 1024, qscale);

  k_vtrans<<<dim3(SS / 64, HH, BB), 256, 0, stream>>>(QKVb, Vtb);
  k_attn<<<dim3(SS / 128, HH, BB), 256, 0, stream>>>(QKVb, Vtb, ctxb);

  k_gemm<1,0><<<dim3(8, 64), 256, 0, stream>>>(
      ctxb, WoT, bo, nullptr, nullptr, x, x1, MM, 1024, 1024, 1.f);

  k_layernorm<<<MM, 256, 0, stream>>>(x1, lnfg, lnfb, hbuf);

  k_ffn_dual<<<dim3(FF / 64, MM / 128), 256, 0, stream>>>(hbuf, WgT, W1T, bg, b1, prod);

  k_gemm<1,0><<<dim3(8, 64), 256, 0, stream>>>(
      prod, W2T, b2, nullptr, nullptr, x1, (float*)d_out, MM, 1024, 4096, 1.f);
}